// Round 1
// baseline (1074.645 us; speedup 1.0000x reference)
//
#include <hip/hip_runtime.h>

#define LL 256
#define NEGV -1000000000.0f
#define LOG2E 1.4426950408889634f
#define LN2 0.6931471805599453f

// off_of(w) = start index of row w in the compact (triangular) chart:
// row w holds columns i in [0, LL-w). Total = 32896 floats = 131584 B.
__device__ __forceinline__ int off_of(int w) {
    return (w << 8) - ((w * (w - 1)) >> 1);
}

__global__ __launch_bounds__(1024, 1)
void cyk_kernel(const float* __restrict__ s, const int* __restrict__ lens,
                float* __restrict__ out) {
    extern __shared__ float chart[];   // 32896 floats, base-2 domain
    const int b   = blockIdx.x;
    const int tid = threadIdx.x;
    const int T   = 1024;
    const float* sb = s + (size_t)b * (LL * LL);

    // ---- init: row 0 = NEG (only read if lens[b]==0) ----
    for (int i = tid; i < LL; i += T) chart[i] = NEGV * LOG2E;

    // ---- stage upper triangle of s_span[b] into compact chart (×log2e) ----
    // coalesced float4 reads of full rows; scatter valid cells to LDS
    for (int idx = tid; idx < (LL * LL) / 4; idx += T) {
        float4 v = reinterpret_cast<const float4*>(sb)[idx];
        int r  = (idx * 4) >> 8;
        int c0 = (idx * 4) & (LL - 1);
        float vv[4] = {v.x, v.y, v.z, v.w};
        #pragma unroll
        for (int q = 0; q < 4; ++q) {
            int w = (c0 + q) - r;
            if (w > 0) chart[off_of(w) + r] = vv[q] * LOG2E;
        }
    }
    __syncthreads();

    const int lanebits = tid & 63;
    (void)lanebits;

    // ---- DP over widths ----
    for (int w = 2; w < LL; ++w) {
        const int ncols = LL - w;
        // G = lanes per column: min(64, P2C(T/ncols), P2C(w-1))
        int G = 1;
        while (G < 64 && G * ncols < T && G < (w - 1)) G <<= 1;
        const int nsg  = T / G;
        const int sg   = tid / G;
        const int l    = tid & (G - 1);
        const int G2   = G * G;
        const int offw = off_of(w);
        const int k0   = 1 + l;
        const int GG   = (G * (G - 1)) >> 1;

        for (int i = sg; i < ncols; i += nsg) {
            // ---- pass 1: lane-local max over strided k ----
            float m = -3.0e38f;
            if (k0 <= w - 1) {
                int aL = off_of(k0) + i;
                int aR = off_of(w - k0) + i + k0;
                int dL = (G << 8) - k0 * G - GG;
                int dR = -(G << 8) + (w - k0 - G) * G + GG + G;
                for (int k = k0; k <= w - 1; k += G) {
                    float x = chart[aL] + chart[aR];
                    m = fmaxf(m, x);
                    aL += dL; dL -= G2;
                    aR += dR; dR -= G2;
                }
            }
            // subgroup max (butterfly: every lane ends with M)
            for (int d = G >> 1; d > 0; d >>= 1)
                m = fmaxf(m, __shfl_xor(m, d));

            // ---- pass 2: sum of 2^(x - M) ----
            float ssum = 0.0f;
            if (k0 <= w - 1) {
                int aL = off_of(k0) + i;
                int aR = off_of(w - k0) + i + k0;
                int dL = (G << 8) - k0 * G - GG;
                int dR = -(G << 8) + (w - k0 - G) * G + GG + G;
                for (int k = k0; k <= w - 1; k += G) {
                    float x = chart[aL] + chart[aR];
                    ssum += exp2f(x - m);
                    aL += dL; dL -= G2;
                    aR += dR; dR -= G2;
                }
            }
            for (int d = G >> 1; d > 0; d >>= 1)
                ssum += __shfl_xor(ssum, d);

            if (l == 0) chart[offw + i] += m + log2f(ssum);
        }
        __syncthreads();
    }

    // ---- output: out[b] = chart[lens[b], 0] * ln2 ----
    if (tid == 0) {
        int len = lens[b];
        len = len < 0 ? 0 : (len > LL - 1 ? LL - 1 : len);
        out[b] = chart[off_of(len)] * LN2;
    }
}

extern "C" void kernel_launch(void* const* d_in, const int* in_sizes, int n_in,
                              void* d_out, int out_size, void* d_ws, size_t ws_size,
                              hipStream_t stream) {
    const float* s_span = (const float*)d_in[0];
    const int*   lens   = (const int*)d_in[1];
    float*       out    = (float*)d_out;
    const int B = in_sizes[1];           // 128
    const int lds_bytes = 32896 * 4;     // 131584 B compact chart

    // allow >64KB dynamic LDS (idempotent, host-side, capture-safe)
    (void)hipFuncSetAttribute((const void*)cyk_kernel,
                              hipFuncAttributeMaxDynamicSharedMemorySize,
                              lds_bytes);

    cyk_kernel<<<B, 1024, lds_bytes, stream>>>(s_span, lens, out);
}

// Round 5
// 546.669 us; speedup vs baseline: 1.9658x; 1.9658x over previous
//
#include <hip/hip_runtime.h>

#define LL 256
#define NEGV -1000000000.0f
#define LOG2E 1.4426950408889634f
#define LN2 0.6931471805599453f

// Compact triangular chart: row w holds its LL-w valid columns.
// off_of(w) = 256w - w(w-1)/2.  Total 32896 dwords.
__device__ __forceinline__ int off_of(int w) {
    return (w << 8) - ((w * (w - 1)) >> 1);
}

#define CHART_SZ 32896
#define SHIFT_OFF 32896          // 256 floats
#define PART_OFF  33152         // 16*256 floats
#define LDS_DWORDS 37248        // total = 148992 bytes

__global__ __launch_bounds__(1024, 1)
void cyk_kernel(const float* __restrict__ s, const int* __restrict__ lens,
                float* __restrict__ out) {
    extern __shared__ float lds[];
    float* chart = lds;
    float* shift = lds + SHIFT_OFF;
    float* part  = lds + PART_OFF;

    const int b    = blockIdx.x;
    const int tid  = threadIdx.x;
    const int wave = tid >> 6;
    const int lane = tid & 63;
    const float* sb = s + (size_t)b * (LL * LL);

    // ---- init row 0 = NEG (read only if lens[b]==0) ----
    for (int i = tid; i < LL; i += 1024) chart[i] = NEGV * LOG2E;

    // ---- stage upper triangle of s_span[b] (×log2e), coalesced float4 ----
    for (int idx = tid; idx < (LL * LL) / 4; idx += 1024) {
        float4 v = reinterpret_cast<const float4*>(sb)[idx];
        int r  = (idx * 4) >> 8;
        int c0 = (idx * 4) & (LL - 1);
        float vv[4] = {v.x, v.y, v.z, v.w};
        #pragma unroll
        for (int q = 0; q < 4; ++q) {
            int w = (c0 + q) - r;
            if (w > 0) chart[off_of(w) + r] = vv[q] * LOG2E;
        }
    }
    __syncthreads();

    // ---- DP over widths ----
    for (int w = 2; w < LL; ++w) {
        const int ncols = LL - w;

        // probe 3 exact split terms -> per-column shift (lower bound on max)
        if (tid < ncols) {
            int c = tid;
            float t1 = chart[off_of(1) + c]     + chart[off_of(w - 1) + c + 1];
            float t2 = chart[off_of(w - 1) + c] + chart[off_of(1) + c + w - 1];
            int km = w >> 1;
            float t3 = chart[off_of(km) + c]    + chart[off_of(w - km) + c + km];
            shift[c] = fmaxf(fmaxf(t1, t2), t3);
        }
        __syncthreads();

        const float sh0 = shift[lane];
        const float sh1 = shift[lane + 64];
        const float sh2 = shift[lane + 128];
        const float sh3 = shift[lane + 192];

        float s0 = 0.f, s1 = 0.f, s2 = 0.f, s3 = 0.f;
        const int k0 = 1 + wave;
        if (k0 <= w - 1) {
            int aL = off_of(k0) + lane;
            int aR = off_of(w - k0) + k0 + lane;
            int dL = 3976 - 16 * k0;          // off(k+16)-off(k)
            int dR = 16 * (w - k0) - 4216;    // off(w-k-16)-off(w-k)+16
            #pragma unroll 2
            for (int k = k0; k <= w - 1; k += 16) {
                float l0 = chart[aL];
                float l1 = chart[aL + 64];
                float l2 = chart[aL + 128];
                float l3 = chart[aL + 192];
                float r0 = chart[aR];
                float r1 = chart[aR + 64];
                float r2 = chart[aR + 128];
                float r3 = chart[aR + 192];
                s0 += __builtin_amdgcn_exp2f(l0 + r0 - sh0);
                s1 += __builtin_amdgcn_exp2f(l1 + r1 - sh1);
                s2 += __builtin_amdgcn_exp2f(l2 + r2 - sh2);
                s3 += __builtin_amdgcn_exp2f(l3 + r3 - sh3);
                aL += dL; dL -= 256;
                aR += dR; dR -= 256;
            }
        }
        part[wave * 256 + lane]       = s0;
        part[wave * 256 + lane + 64]  = s1;
        part[wave * 256 + lane + 128] = s2;
        part[wave * 256 + lane + 192] = s3;
        __syncthreads();

        // combine 16 wave-partials per column; add span (preloaded in chart)
        if (tid < ncols) {
            float tot = 0.f;
            #pragma unroll
            for (int t = 0; t < 16; ++t) tot += part[t * 256 + tid];
            chart[off_of(w) + tid] += shift[tid] + __builtin_amdgcn_logf(tot);
        }
        __syncthreads();
    }

    // ---- output ----
    if (tid == 0) {
        int len = lens[b];
        len = len < 0 ? 0 : (len > LL - 1 ? LL - 1 : len);
        out[b] = chart[off_of(len)] * LN2;
    }
}

extern "C" void kernel_launch(void* const* d_in, const int* in_sizes, int n_in,
                              void* d_out, int out_size, void* d_ws, size_t ws_size,
                              hipStream_t stream) {
    const float* s_span = (const float*)d_in[0];
    const int*   lens   = (const int*)d_in[1];
    float*       out    = (float*)d_out;
    const int B = in_sizes[1];               // 128
    const int lds_bytes = LDS_DWORDS * 4;    // 148992 B

    (void)hipFuncSetAttribute((const void*)cyk_kernel,
                              hipFuncAttributeMaxDynamicSharedMemorySize,
                              lds_bytes);

    cyk_kernel<<<B, 1024, lds_bytes, stream>>>(s_span, lens, out);
}

// Round 7
// 412.670 us; speedup vs baseline: 2.6041x; 1.3247x over previous
//
#include <hip/hip_runtime.h>

#define LL 256
#define NEGV -1000000000.0f
#define LOG2E 1.4426950408889634f
#define LN2 0.6931471805599453f

// Compact triangular chart: row w holds its LL-w valid columns.
// off_of(w) = 256w - w(w-1)/2.  Total 32896 dwords.
__device__ __forceinline__ int off_of(int w) {
    return (w << 8) - ((w * (w - 1)) >> 1);
}

#define SHIFT_OFF 32896          // 256 floats
#define PART_OFF  33152         // 16*256 floats
#define LDS_DWORDS 37248        // total = 148992 bytes

// Inner k-split loop, specialized on number of active 64-column slots.
template<int NC>
__device__ __forceinline__ void inner_loop(const float* chart, const float* shift,
                                           float* part, int w, int wave, int lane) {
    float s[NC];
    float sh[NC];
    #pragma unroll
    for (int q = 0; q < NC; ++q) { s[q] = 0.f; sh[q] = shift[lane + 64 * q]; }

    const int k0 = 1 + wave;
    if (k0 <= w - 1) {
        int aL = off_of(k0) + lane;
        int aR = off_of(w - k0) + k0 + lane;
        int dL = 3976 - 16 * k0;          // off(k+16)-off(k)
        int dR = 16 * (w - k0) - 4216;    // off(w-k-16)-off(w-k)+16
        for (int k = k0; k <= w - 1; k += 16) {
            #pragma unroll
            for (int q = 0; q < NC; ++q) {
                float l = chart[aL + 64 * q];
                float r = chart[aR + 64 * q];
                s[q] += __builtin_amdgcn_exp2f(l + r - sh[q]);
            }
            aL += dL; dL -= 256;
            aR += dR; dR -= 256;
        }
    }
    #pragma unroll
    for (int q = 0; q < NC; ++q) part[wave * 256 + lane + 64 * q] = s[q];
}

__global__ __launch_bounds__(1024, 1)
void cyk_kernel(const float* __restrict__ s, const int* __restrict__ lens,
                float* __restrict__ out) {
    extern __shared__ float lds[];
    float* chart = lds;
    float* shift = lds + SHIFT_OFF;
    float* part  = lds + PART_OFF;

    const int b    = blockIdx.x;
    const int tid  = threadIdx.x;
    const int wave = tid >> 6;
    const int lane = tid & 63;
    const float* sb = s + (size_t)b * (LL * LL);

    // ---- init row 0 = NEG (read only if lens[b]==0) ----
    for (int i = tid; i < LL; i += 1024) chart[i] = NEGV * LOG2E;

    // ---- stage upper triangle of s_span[b] (×log2e), coalesced float4 ----
    for (int idx = tid; idx < (LL * LL) / 4; idx += 1024) {
        float4 v = reinterpret_cast<const float4*>(sb)[idx];
        int r  = (idx * 4) >> 8;
        int c0 = (idx * 4) & (LL - 1);
        float vv[4] = {v.x, v.y, v.z, v.w};
        #pragma unroll
        for (int q = 0; q < 4; ++q) {
            int w = (c0 + q) - r;
            if (w > 0) chart[off_of(w) + r] = vv[q] * LOG2E;
        }
    }
    __syncthreads();

    // ---- bootstrap shift for w=2: only split k=1 (rows 1,1) ----
    if (tid < LL - 2) shift[tid] = chart[256 + tid] + chart[256 + tid + 1];
    __syncthreads();

    // ---- DP over widths: 2 barriers/step ----
    for (int w = 2; w < LL; ++w) {
        const int ncols = LL - w;
        const int nslots = (ncols + 63) >> 6;

        switch (nslots) {
            case 4: inner_loop<4>(chart, shift, part, w, wave, lane); break;
            case 3: inner_loop<3>(chart, shift, part, w, wave, lane); break;
            case 2: inner_loop<2>(chart, shift, part, w, wave, lane); break;
            default: inner_loop<1>(chart, shift, part, w, wave, lane); break;
        }
        __syncthreads();

        // combine 16 wave-partials; write row w; compute shift for width w+1
        if (tid < ncols) {
            float tot = 0.f;
            #pragma unroll
            for (int t = 0; t < 16; ++t) tot += part[t * 256 + tid];
            float newv = chart[off_of(w) + tid] + shift[tid]
                       + __builtin_amdgcn_logf(tot);
            chart[off_of(w) + tid] = newv;

            // shift for width w+1 at column tid (garbage for tid==ncols-1: unused)
            // probe A: split k=w -> left = row w col tid (register), right = row 1
            float p1 = newv + chart[256 + tid + w];
            float p2 = p1;
            if (w >= 3) {
                // probe B: mid split km=(w+1)>>1; rows <= w-1, stable this phase
                int km = (w + 1) >> 1;
                p2 = chart[off_of(km) + tid] + chart[off_of(w + 1 - km) + tid + km];
            }
            shift[tid] = fmaxf(p1, p2);
        }
        __syncthreads();
    }

    // ---- output ----
    if (tid == 0) {
        int len = lens[b];
        len = len < 0 ? 0 : (len > LL - 1 ? LL - 1 : len);
        out[b] = chart[off_of(len)] * LN2;
    }
}

extern "C" void kernel_launch(void* const* d_in, const int* in_sizes, int n_in,
                              void* d_out, int out_size, void* d_ws, size_t ws_size,
                              hipStream_t stream) {
    const float* s_span = (const float*)d_in[0];
    const int*   lens   = (const int*)d_in[1];
    float*       out    = (float*)d_out;
    const int B = in_sizes[1];               // 128
    const int lds_bytes = LDS_DWORDS * 4;    // 148992 B

    (void)hipFuncSetAttribute((const void*)cyk_kernel,
                              hipFuncAttributeMaxDynamicSharedMemorySize,
                              lds_bytes);

    cyk_kernel<<<B, 1024, lds_bytes, stream>>>(s_span, lens, out);
}